// Round 3
// baseline (373.219 us; speedup 1.0000x reference)
//
#include <hip/hip_runtime.h>
#include <math.h>

// XMIX mixing network — split-bf16 MFMA, occupancy rework.
// TB=32 samples/block, 1024 blocks x 512 threads, LDS 80KB -> 2 blocks/CU.
// States A-fragments loaded directly from global (split in registers) — no P0.
// Prep kernel = LDS-tiled transpose (coalesced both sides).
// R2 fix: prep source pointer must be offset by the K-tile row (k0*snc);
// destination-only offset fed rows 0..63 into every K-tile (absmax 3.0).

#define NB 32768
#define TB 32
#define THREADS 512
#define NBLOCKS (NB / TB)   // 1024

typedef short sh8 __attribute__((ext_vector_type(8)));  // 8 bf16 (4 VGPR)
typedef float f4 __attribute__((ext_vector_type(4)));   // MFMA C/D
typedef unsigned short ush;

// ---- workspace layout (ushort units). WT[col][k] hi/lo planes ----
#define OFF_WCAT_H 0                        // [640][512]  (W1a|Wfa|Wb1|Wv1|pad)
#define OFF_WCAT_L (640 * 512)
#define OFF_W1B_H  (2 * 640 * 512)          // [256][256]
#define OFF_W1B_L  (OFF_W1B_H + 256 * 256)
#define OFF_WFB_H  (OFF_W1B_L + 256 * 256)  // [32][256]
#define OFF_WFB_L  (OFF_WFB_H + 32 * 256)
#define OFF_TOK_H  (OFF_WFB_L + 32 * 256)   // [32][64]
#define OFF_TOK_L  (OFF_TOK_H + 32 * 64)
#define OFF_YFC_H  (OFF_TOK_L + 32 * 64)    // [64][32]
#define OFF_YFC_L  (OFF_YFC_H + 64 * 32)
// total shorts = 811008 (1.62 MB of d_ws)

__device__ __forceinline__ ush f2bf(float x) {
    unsigned u = __float_as_uint(x);
    u += 0x7fffu + ((u >> 16) & 1u);        // RNE
    return (ush)(u >> 16);
}
__device__ __forceinline__ float bf2f(ush h) {
    return __uint_as_float(((unsigned)h) << 16);
}
__device__ __forceinline__ void splitbf(float x, ush& h, ush& l) {
    h = f2bf(x);
    l = f2bf(x - bf2f(h));
}
__device__ __forceinline__ f4 mfma(sh8 a, sh8 b, f4 c) {
    return __builtin_amdgcn_mfma_f32_16x16x32_bf16(a, b, c, 0, 0, 0);
}
__device__ __forceinline__ void split8(const float4 v0, const float4 v1, sh8& Ah, sh8& Al) {
    ush h, l;
    splitbf(v0.x, h, l); Ah[0] = (short)h; Al[0] = (short)l;
    splitbf(v0.y, h, l); Ah[1] = (short)h; Al[1] = (short)l;
    splitbf(v0.z, h, l); Ah[2] = (short)h; Al[2] = (short)l;
    splitbf(v0.w, h, l); Ah[3] = (short)h; Al[3] = (short)l;
    splitbf(v1.x, h, l); Ah[4] = (short)h; Al[4] = (short)l;
    splitbf(v1.y, h, l); Ah[5] = (short)h; Al[5] = (short)l;
    splitbf(v1.z, h, l); Ah[6] = (short)h; Al[6] = (short)l;
    splitbf(v1.w, h, l); Ah[7] = (short)h; Al[7] = (short)l;
}

// LDS swizzles (write and read use the same bijection).
__device__ __forceinline__ unsigned swY(unsigned a) {   // 1024B-stride sample rows
    return a ^ (((((a >> 10) & 7) ^ ((a >> 7) & 7)) << 4));
}
__device__ __forceinline__ unsigned swH(unsigned a) {   // 512B-stride rows
    return a ^ (((a >> 9) & 7) << 4);
}
__device__ __forceinline__ unsigned swS(unsigned a) {   // 64B-stride scratch
    return a ^ (((a >> 7) & 3) << 4);
}

// ---------------- prep: LDS-tiled transpose + hi/lo split ----------------
// src must already point at the first source row of this K-tile.
__device__ void tileT(const float* src, int snc, int scol0, int ncol, int nk,
                      ush* dH, ush* dL, int dstride, float (*T)[68])
{
    const int tid = threadIdx.x;
    const int nc4 = ncol >> 2;
    const int s_r = (nc4 == 16) ? 4 : 3;
    const int items_r = nk * nc4;
    for (int i = tid; i < items_r; i += 256) {
        const int r = i >> s_r, c4 = i & (nc4 - 1);
        const float4 v = *(const float4*)(src + r * snc + scol0 + c4 * 4);
        T[r][c4 * 4 + 0] = v.x; T[r][c4 * 4 + 1] = v.y;
        T[r][c4 * 4 + 2] = v.z; T[r][c4 * 4 + 3] = v.w;
    }
    __syncthreads();
    const int nk4 = nk >> 2;
    const int s_w = (nk4 == 16) ? 4 : 3;
    const int items_w = ncol * nk4;
    for (int i = tid; i < items_w; i += 256) {
        const int c = i >> s_w, kq = i & (nk4 - 1);
        ushort4 hv, lv;
        ush h, lo;
        splitbf(T[kq * 4 + 0][c], h, lo); hv.x = h; lv.x = lo;
        splitbf(T[kq * 4 + 1][c], h, lo); hv.y = h; lv.y = lo;
        splitbf(T[kq * 4 + 2][c], h, lo); hv.z = h; lv.z = lo;
        splitbf(T[kq * 4 + 3][c], h, lo); hv.w = h; lv.w = lo;
        *(ushort4*)(dH + c * dstride + kq * 4) = hv;
        *(ushort4*)(dL + c * dstride + kq * 4) = lv;
    }
    __syncthreads();
}

__global__ __launch_bounds__(256) void xmix_prep(
    const float* __restrict__ W_tok, const float* __restrict__ W_yfc,
    const float* __restrict__ W1a, const float* __restrict__ W1b,
    const float* __restrict__ Wfa, const float* __restrict__ Wfb,
    const float* __restrict__ Wb1, const float* __restrict__ Wv1,
    ush* __restrict__ ws)
{
    __shared__ float T[64][68];
    const int b = blockIdx.x;
    if (b < 80) {                    // Wcat [512 k][640 col]
        const int kt = b / 10, ct = b % 10;
        const int k0 = kt * 64;
        if (ct < 4) {
            tileT(W1a + (size_t)k0 * 256, 256, ct * 64, 64, 64,
                  ws + OFF_WCAT_H + (ct * 64) * 512 + k0,
                  ws + OFF_WCAT_L + (ct * 64) * 512 + k0, 512, T);
        } else if (ct < 8) {
            tileT(Wfa + (size_t)k0 * 256, 256, (ct - 4) * 64, 64, 64,
                  ws + OFF_WCAT_H + (ct * 64) * 512 + k0,
                  ws + OFF_WCAT_L + (ct * 64) * 512 + k0, 512, T);
        } else if (ct == 8) {
            tileT(Wb1 + (size_t)k0 * 32, 32, 0, 32, 64,
                  ws + OFF_WCAT_H + 512 * 512 + k0,
                  ws + OFF_WCAT_L + 512 * 512 + k0, 512, T);
            tileT(Wv1 + (size_t)k0 * 32, 32, 0, 32, 64,
                  ws + OFF_WCAT_H + 544 * 512 + k0,
                  ws + OFF_WCAT_L + 544 * 512 + k0, 512, T);
        } else {                     // zero pad cols 576..639
            const int tid = threadIdx.x;
            const ushort4 z = {0, 0, 0, 0};
            for (int i = tid; i < 64 * 16; i += 256) {
                const int c = i >> 4, kq = i & 15;
                *(ushort4*)(ws + OFF_WCAT_H + (576 + c) * 512 + k0 + kq * 4) = z;
                *(ushort4*)(ws + OFF_WCAT_L + (576 + c) * 512 + k0 + kq * 4) = z;
            }
        }
    } else if (b < 96) {             // W1b [256][256]
        const int i = b - 80, kt = i >> 2, ct = i & 3;
        tileT(W1b + (size_t)(kt * 64) * 256, 256, ct * 64, 64, 64,
              ws + OFF_W1B_H + (ct * 64) * 256 + kt * 64,
              ws + OFF_W1B_L + (ct * 64) * 256 + kt * 64, 256, T);
    } else if (b < 100) {            // Wfb [256][32]
        const int kt = b - 96;
        tileT(Wfb + (size_t)(kt * 64) * 32, 32, 0, 32, 64,
              ws + OFF_WFB_H + kt * 64,
              ws + OFF_WFB_L + kt * 64, 256, T);
    } else if (b == 100) {           // W_tok [64][32]
        tileT(W_tok, 32, 0, 32, 64, ws + OFF_TOK_H, ws + OFF_TOK_L, 64, T);
    } else {                         // W_yfc [32][64]
        tileT(W_yfc, 64, 0, 64, 32, ws + OFF_YFC_H, ws + OFF_YFC_L, 32, T);
    }
}

// ---------------- main fused kernel ----------------
__global__ __launch_bounds__(THREADS, 4) void xmix_mfma(
    const float* __restrict__ agent_qs,
    const float* __restrict__ states,
    const ush* __restrict__ ws,
    const float* __restrict__ b_tok, const float* __restrict__ b_yfc,
    const float* __restrict__ b1a,  const float* __restrict__ b1b,
    const float* __restrict__ bfa,  const float* __restrict__ bfb,
    const float* __restrict__ bb1,  const float* __restrict__ bv1,
    const float* __restrict__ Wv2,  const float* __restrict__ bv2,
    float* __restrict__ out)
{
    // BB phases:
    //  (1) Y-split bf16: hi [32][512] @0 (32KB), lo @32768
    //  (2) H1-hi @0 (16KB), H1-lo @16384, HF-hi @32768, HF-lo @49152
    //  (3) w1 f32 [32][260] @0 (33280), wf [32][36] @33280,
    //      hidden [32][36] @37888, tprod @42496  (end 47104)
    __shared__ __align__(16) unsigned char BBs[65536];
    // SM: e-scratch (P1/P2: 2KB/wave) -> b1 f32 [32][36] @0, v1 @4608
    __shared__ __align__(16) unsigned char SMs[16384];

    const int tid = threadIdx.x;
    const int wv = tid >> 6;          // wave 0..7
    const int l   = tid & 63;
    const int l16 = l & 15;
    const int lq  = l >> 4;
    const int base = blockIdx.x * TB;
    const f4 fzero = {0.f, 0.f, 0.f, 0.f};

    // ---- P1+P2: e = relu(s@W_tok+b) ; y = relu(e@W_yfc+b) -> Y-split in BB ----
    // A for P1 comes straight from global (register split) — states never in LDS.
    {
        const ush* tokH = ws + OFF_TOK_H;
        const ush* tokL = ws + OFF_TOK_L;
        const ush* yfcH = ws + OFF_YFC_H;
        const ush* yfcL = ws + OFF_YFC_L;
        unsigned char* scr = &SMs[wv * 2048];   // e-split: hi[16][32] @0, lo @1024

        float btok[2];
        btok[0] = b_tok[l16]; btok[1] = b_tok[16 + l16];
        float byfc[4];
        #pragma unroll
        for (int n = 0; n < 4; n++) byfc[n] = b_yfc[n * 16 + l16];

        sh8 TBh[2][2], TBl[2][2];
        #pragma unroll
        for (int n = 0; n < 2; n++)
            #pragma unroll
            for (int kc = 0; kc < 2; kc++) {
                const int coff = (n * 16 + l16) * 64 + kc * 32 + lq * 8;
                TBh[n][kc] = *(const sh8*)(tokH + coff);
                TBl[n][kc] = *(const sh8*)(tokL + coff);
            }
        sh8 YBh[4], YBl[4];
        #pragma unroll
        for (int n = 0; n < 4; n++) {
            const int coff = (n * 16 + l16) * 32 + lq * 8;
            YBh[n] = *(const sh8*)(yfcH + coff);
            YBl[n] = *(const sh8*)(yfcL + coff);
        }

        #pragma unroll
        for (int i = 0; i < 2; i++) {
            const int rt = wv * 2 + i;                 // e-row tile (0..15)
            const int r = rt * 16 + l16;               // agent-row 0..255
            const float* srow = states + (size_t)(base + (r >> 3)) * 512 + (r & 7) * 64;
            f4 eacc[2] = {fzero, fzero};
            #pragma unroll
            for (int kc = 0; kc < 2; kc++) {
                const float4 v0 = *(const float4*)(srow + kc * 32 + lq * 8);
                const float4 v1 = *(const float4*)(srow + kc * 32 + lq * 8 + 4);
                sh8 Ah, Al;
                split8(v0, v1, Ah, Al);
                #pragma unroll
                for (int n = 0; n < 2; n++) {
                    eacc[n] = mfma(Ah, TBh[n][kc], eacc[n]);
                    eacc[n] = mfma(Ah, TBl[n][kc], eacc[n]);
                    eacc[n] = mfma(Al, TBh[n][kc], eacc[n]);
                }
            }
            // e -> per-wave scratch (split, swizzled)
            #pragma unroll
            for (int n = 0; n < 2; n++)
                #pragma unroll
                for (int j = 0; j < 4; j++) {
                    const float e = fmaxf(eacc[n][j] + btok[n], 0.f);
                    const unsigned sa = swS((unsigned)((lq * 4 + j) * 64 + (n * 16 + l16) * 2));
                    ush hh, ll; splitbf(e, hh, ll);
                    *(ush*)(scr + sa)        = hh;
                    *(ush*)(scr + 1024 + sa) = ll;
                }
            // P2: y-tile = e-tile @ W_yfc
            f4 yacc[4] = {fzero, fzero, fzero, fzero};
            {
                const unsigned sa = swS((unsigned)(l16 * 64 + lq * 16));
                const sh8 Ah = *(const sh8*)(scr + sa);
                const sh8 Al = *(const sh8*)(scr + 1024 + sa);
                #pragma unroll
                for (int n = 0; n < 4; n++) {
                    yacc[n] = mfma(Ah, YBh[n], yacc[n]);
                    yacc[n] = mfma(Ah, YBl[n], yacc[n]);
                    yacc[n] = mfma(Al, YBh[n], yacc[n]);
                }
            }
            // y -> Y-split planes
            #pragma unroll
            for (int n = 0; n < 4; n++)
                #pragma unroll
                for (int j = 0; j < 4; j++) {
                    const float y = fmaxf(yacc[n][j] + byfc[n], 0.f);
                    const int rr = rt * 16 + lq * 4 + j;   // agent-row
                    const int ff = n * 16 + l16;
                    const unsigned sa = swY((unsigned)(rr * 128 + ff * 2));
                    ush hh, ll; splitbf(y, hh, ll);
                    *(ush*)(&BBs[sa])         = hh;
                    *(ush*)(&BBs[32768 + sa]) = ll;
                }
        }
    }
    __syncthreads();

    // ---- P3: Y[32,512] @ Wcat[512,640] -> H1|HF|b1|v1 ----
    f4 acc3[2][5];
    #pragma unroll
    for (int m = 0; m < 2; m++)
        #pragma unroll
        for (int t = 0; t < 5; t++) acc3[m][t] = fzero;
    {
        const ush* wcH = ws + OFF_WCAT_H;
        const ush* wcL = ws + OFF_WCAT_L;
        int cb[5];
        #pragma unroll
        for (int t = 0; t < 5; t++) cb[t] = ((wv * 5 + t) * 16 + l16) * 512;
        const int rowb0 = l16 * 1024;
        const int rowb1 = (16 + l16) * 1024;

        #pragma unroll 2
        for (int kc = 0; kc < 16; kc++) {
            const int ko = kc * 32 + lq * 8;
            sh8 BH[5], BL[5];
            #pragma unroll
            for (int t = 0; t < 5; t++) BH[t] = *(const sh8*)(wcH + cb[t] + ko);
            const unsigned sa0 = swY((unsigned)(rowb0 + ko * 2));
            const unsigned sa1 = swY((unsigned)(rowb1 + ko * 2));
            const sh8 Ah0 = *(const sh8*)(&BBs[sa0]);
            const sh8 Al0 = *(const sh8*)(&BBs[32768 + sa0]);
            const sh8 Ah1 = *(const sh8*)(&BBs[sa1]);
            const sh8 Al1 = *(const sh8*)(&BBs[32768 + sa1]);
            #pragma unroll
            for (int t = 0; t < 5; t++) {
                acc3[0][t] = mfma(Ah0, BH[t], acc3[0][t]);
                acc3[1][t] = mfma(Ah1, BH[t], acc3[1][t]);
            }
            #pragma unroll
            for (int t = 0; t < 5; t++) BL[t] = *(const sh8*)(wcL + cb[t] + ko);
            #pragma unroll
            for (int t = 0; t < 5; t++) {
                acc3[0][t] = mfma(Al0, BH[t], acc3[0][t]);
                acc3[1][t] = mfma(Al1, BH[t], acc3[1][t]);
            }
            #pragma unroll
            for (int t = 0; t < 5; t++) {
                acc3[0][t] = mfma(Ah0, BL[t], acc3[0][t]);
                acc3[1][t] = mfma(Ah1, BL[t], acc3[1][t]);
            }
        }
    }
    __syncthreads();   // all waves done reading Y

    // ---- P3 epilogue: acc3 -> H1-split / HF-split / b1 / v1 ----
    {
        #pragma unroll
        for (int t = 0; t < 5; t++) {
            const int gt = wv * 5 + t;
            const int cg = gt * 16 + l16;
            if (gt < 16) {                       // H1 = relu(y@W1a + b1a)
                const float bias = b1a[cg];
                #pragma unroll
                for (int m = 0; m < 2; m++)
                    #pragma unroll
                    for (int j = 0; j < 4; j++) {
                        const int row = m * 16 + lq * 4 + j;
                        const float h = fmaxf(acc3[m][t][j] + bias, 0.f);
                        ush hh, ll; splitbf(h, hh, ll);
                        const unsigned sa = swH((unsigned)(row * 512 + cg * 2));
                        *(ush*)(&BBs[sa])         = hh;
                        *(ush*)(&BBs[16384 + sa]) = ll;
                    }
            } else if (gt < 32) {                // HF = relu(y@Wfa + bfa)
                const int c = cg - 256;
                const float bias = bfa[c];
                #pragma unroll
                for (int m = 0; m < 2; m++)
                    #pragma unroll
                    for (int j = 0; j < 4; j++) {
                        const int row = m * 16 + lq * 4 + j;
                        const float h = fmaxf(acc3[m][t][j] + bias, 0.f);
                        ush hh, ll; splitbf(h, hh, ll);
                        const unsigned sa = swH((unsigned)(row * 512 + c * 2));
                        *(ush*)(&BBs[32768 + sa]) = hh;
                        *(ush*)(&BBs[49152 + sa]) = ll;
                    }
            } else if (gt < 34) {                // b1 = y@Wb1 + bb1 (no relu)
                const int c = cg - 512;
                const float bias = bb1[c];
                #pragma unroll
                for (int m = 0; m < 2; m++)
                    #pragma unroll
                    for (int j = 0; j < 4; j++) {
                        const int row = m * 16 + lq * 4 + j;
                        *(float*)(&SMs[(row * 36 + c) * 4]) = acc3[m][t][j] + bias;
                    }
            } else if (gt < 36) {                // v1 = relu(y@Wv1 + bv1)
                const int c = cg - 544;
                const float bias = bv1[c];
                #pragma unroll
                for (int m = 0; m < 2; m++)
                    #pragma unroll
                    for (int j = 0; j < 4; j++) {
                        const int row = m * 16 + lq * 4 + j;
                        *(float*)(&SMs[4608 + (row * 36 + c) * 4]) =
                            fmaxf(acc3[m][t][j] + bias, 0.f);
                    }
            } // gt>=36: pad, discard
        }
    }
    __syncthreads();

    // ---- P4: w1 = |H1@W1b + b1b| ; wf = |HF@Wfb + bfb| ----
    f4 acc4[2][2];
    #pragma unroll
    for (int m = 0; m < 2; m++) { acc4[m][0] = fzero; acc4[m][1] = fzero; }
    f4 accw = fzero;
    {
        const ush* w1H = ws + OFF_W1B_H;
        const ush* w1L = ws + OFF_W1B_L;
        const ush* wfH = ws + OFF_WFB_H;
        const ush* wfL = ws + OFF_WFB_L;
        const int cb0 = ((wv * 2 + 0) * 16 + l16) * 256;
        const int cb1 = ((wv * 2 + 1) * 16 + l16) * 256;
        const int mw = wv & 1, nw = (wv >> 1) & 1;
        const int cbw = (nw * 16 + l16) * 256;
        const bool dowf = (wv < 4);
        #pragma unroll 2
        for (int kc = 0; kc < 8; kc++) {
            const int ko = kc * 32 + lq * 8;
            const sh8 B0h = *(const sh8*)(w1H + cb0 + ko);
            const sh8 B1h = *(const sh8*)(w1H + cb1 + ko);
            const sh8 B0l = *(const sh8*)(w1L + cb0 + ko);
            const sh8 B1l = *(const sh8*)(w1L + cb1 + ko);
            const unsigned sa0 = swH((unsigned)(l16 * 512 + ko * 2));
            const unsigned sa1 = swH((unsigned)((16 + l16) * 512 + ko * 2));
            const sh8 Ah0 = *(const sh8*)(&BBs[sa0]);
            const sh8 Al0 = *(const sh8*)(&BBs[16384 + sa0]);
            const sh8 Ah1 = *(const sh8*)(&BBs[sa1]);
            const sh8 Al1 = *(const sh8*)(&BBs[16384 + sa1]);
            acc4[0][0] = mfma(Ah0, B0h, acc4[0][0]);
            acc4[1][0] = mfma(Ah1, B0h, acc4[1][0]);
            acc4[0][1] = mfma(Ah0, B1h, acc4[0][1]);
            acc4[1][1] = mfma(Ah1, B1h, acc4[1][1]);
            acc4[0][0] = mfma(Al0, B0h, acc4[0][0]);
            acc4[1][0] = mfma(Al1, B0h, acc4[1][0]);
            acc4[0][1] = mfma(Al0, B1h, acc4[0][1]);
            acc4[1][1] = mfma(Al1, B1h, acc4[1][1]);
            acc4[0][0] = mfma(Ah0, B0l, acc4[0][0]);
            acc4[1][0] = mfma(Ah1, B0l, acc4[1][0]);
            acc4[0][1] = mfma(Ah0, B1l, acc4[0][1]);
            acc4[1][1] = mfma(Ah1, B1l, acc4[1][1]);
            if (dowf) {
                const unsigned saw = swH((unsigned)((mw * 16 + l16) * 512 + ko * 2));
                const sh8 Awh = *(const sh8*)(&BBs[32768 + saw]);
                const sh8 Awl = *(const sh8*)(&BBs[49152 + saw]);
                const sh8 Wh = *(const sh8*)(wfH + cbw + ko);
                const sh8 Wl = *(const sh8*)(wfL + cbw + ko);
                accw = mfma(Awh, Wh, accw);
                accw = mfma(Awl, Wh, accw);
                accw = mfma(Awh, Wl, accw);
            }
        }
    }
    __syncthreads();   // H1/HF consumed

    // w1/wf -> f32 LDS (padded strides: 260 / 36 to kill bank conflicts)
    {
        #pragma unroll
        for (int t = 0; t < 2; t++) {
            const int col = (wv * 2 + t) * 16 + l16;
            const float bias = b1b[col];
            #pragma unroll
            for (int m = 0; m < 2; m++)
                #pragma unroll
                for (int j = 0; j < 4; j++) {
                    const int row = m * 16 + lq * 4 + j;
                    *(float*)(&BBs[(row * 260 + col) * 4]) =
                        fabsf(acc4[m][t][j] + bias);
                }
        }
        if (wv < 4) {
            const int col = ((wv >> 1) & 1) * 16 + l16;
            const float bias = bfb[col];
            const int mw = wv & 1;
            #pragma unroll
            for (int j = 0; j < 4; j++) {
                const int row = mw * 16 + lq * 4 + j;
                *(float*)(&BBs[33280 + (row * 36 + col) * 4]) =
                    fabsf(accw[j] + bias);
            }
        }
    }
    __syncthreads();

    // ---- P5: epilogue (elu, delu, q_tot, grad) ----
    {
        const int s = tid >> 4, li = tid & 15;
        const int b = base + s;
        float q[8];
        #pragma unroll
        for (int a = 0; a < 8; a++) q[a] = agent_qs[(size_t)b * 8 + a];
        const float* w1p = (const float*)(&BBs[0]);        // [32][260]
        const float* wfp = (const float*)(&BBs[33280]);    // [32][36]
        const float* b1p = (const float*)(&SMs[0]);        // [32][36]
        float* hidp = (float*)(&BBs[37888]);
        float* tpp  = (float*)(&BBs[42496]);
        #pragma unroll
        for (int ii = 0; ii < 2; ii++) {
            const int e = li + 16 * ii;
            float z = b1p[s * 36 + e];
            #pragma unroll
            for (int a = 0; a < 8; a++) z = fmaf(q[a], w1p[s * 260 + a * 32 + e], z);
            const float h = (z > 0.f) ? z : (expf(z) - 1.f);   // elu
            const float d = (h < 0.f) ? expf(h) : 1.f;          // delu of elu OUTPUT (ref!)
            hidp[s * 36 + e] = h;
            tpp[s * 36 + e] = d * wfp[s * 36 + e];
        }
    }
    __syncthreads();
    {
        const float* w1p = (const float*)(&BBs[0]);
        const float* wfp = (const float*)(&BBs[33280]);
        const float* v1p = (const float*)(&SMs[4608]);
        const float* hidp = (const float*)(&BBs[37888]);
        const float* tpp  = (const float*)(&BBs[42496]);
        if (tid < 256) {
            const int s = tid >> 3, a = tid & 7;
            const int b = base + s;
            float g = 0.f;
            #pragma unroll
            for (int e = 0; e < 32; e++)
                g = fmaf(w1p[s * 260 + a * 32 + e], tpp[s * 36 + e], g);
            out[NB + (size_t)b * 8 + a] = g;
        }
        if (tid < 32) {
            const int s2 = tid, b2 = base + s2;
            float v = bv2[0];
            #pragma unroll
            for (int e = 0; e < 32; e++) v = fmaf(v1p[s2 * 36 + e], Wv2[e], v);
            float qt = v;
            #pragma unroll
            for (int e = 0; e < 32; e++)
                qt = fmaf(hidp[s2 * 36 + e], wfp[s2 * 36 + e], qt);
            out[b2] = qt;
        }
    }
}

extern "C" void kernel_launch(void* const* d_in, const int* in_sizes, int n_in,
                              void* d_out, int out_size, void* d_ws, size_t ws_size,
                              hipStream_t stream) {
    const float* agent_qs = (const float*)d_in[0];
    // d_in[1] = hist (unused by reference)
    const float* states   = (const float*)d_in[2];
    // d_in[3] = obs (unused by reference)
    const float* W_tok = (const float*)d_in[4];
    const float* b_tok = (const float*)d_in[5];
    const float* W_yfc = (const float*)d_in[6];
    const float* b_yfc = (const float*)d_in[7];
    const float* W1a   = (const float*)d_in[8];
    const float* b1a   = (const float*)d_in[9];
    const float* W1b   = (const float*)d_in[10];
    const float* b1b   = (const float*)d_in[11];
    const float* Wfa   = (const float*)d_in[12];
    const float* bfa   = (const float*)d_in[13];
    const float* Wfb   = (const float*)d_in[14];
    const float* bfb   = (const float*)d_in[15];
    const float* Wb1   = (const float*)d_in[16];
    const float* bb1   = (const float*)d_in[17];
    const float* Wv1   = (const float*)d_in[18];
    const float* bv1   = (const float*)d_in[19];
    const float* Wv2   = (const float*)d_in[20];
    const float* bv2   = (const float*)d_in[21];
    float* out = (float*)d_out;
    ush* ws = (ush*)d_ws;   // needs 1,622,016 B

    xmix_prep<<<102, 256, 0, stream>>>(W_tok, W_yfc, W1a, W1b, Wfa, Wfb, Wb1, Wv1, ws);
    xmix_mfma<<<NBLOCKS, THREADS, 0, stream>>>(
        agent_qs, states, ws, b_tok, b_yfc, b1a, b1b, bfa, bfb,
        bb1, bv1, Wv2, bv2, out);
}